// Round 11
// baseline (791.530 us; speedup 1.0000x reference)
//
#include <hip/hip_runtime.h>
#include <stdint.h>

// Problem constants
#define T_TOK 16384   // B*S
#define DDIM  1024
#define FDIM  2048
#define NEXP  8
#define MAX_SLOTS 33792  // T*K (32768) + E*127 padding, rounded to 128
#define NMT (MAX_SLOTS / 128)  // 264 mtiles

typedef __attribute__((ext_vector_type(8))) short bf16x8;
typedef __attribute__((ext_vector_type(4))) float f32x4;
typedef __attribute__((ext_vector_type(16))) float f32x16;

typedef __attribute__((address_space(1))) void gvoid_t;
typedef __attribute__((address_space(3))) void lvoid_t;

// meta layout (ints): [0..255] counts padded (stride 32), [256..511] cursors padded,
// [512..520] offp, [544..544+NMT) mexp
#define META_CNT 0
#define META_CUR 256
#define META_OFF 512
#define META_MEXP 544

__device__ __forceinline__ void cp16(void* lds, const void* g) {
  __builtin_amdgcn_global_load_lds((gvoid_t*)g, (lvoid_t*)lds, 16, 0, 0);
}

__device__ __forceinline__ unsigned short f2bf(float f) {
  union { float f; unsigned int u; } v; v.f = f;
  unsigned int u = v.u;
  return (unsigned short)((u + 0x7fffu + ((u >> 16) & 1u)) >> 16);  // RNE
}

// bijective XCD-chunk remap (m204) — gemm2 ONLY (h-tile locality; measured win R4).
// gemm1 keeps the natural 2D grid: bid%8 = nb%8 -> weight-column L2 affinity (measured R3).
__device__ __forceinline__ int xcd_remap(int bid, int nwg) {
  int xcd = bid & 7, i = bid >> 3;
  int q = nwg >> 3, r = nwg & 7;
  int base = (xcd < r) ? xcd * (q + 1) : r * (q + 1) + (xcd - r) * q;
  return base + i;
}

// ---------------- router: fp32 logits, top-2 weights; emits xb = bf16(x); fused histogram ----------------
__global__ void router_kernel(const float* __restrict__ x, const float* __restrict__ rw,
                              int* __restrict__ tk_idx, float* __restrict__ tk_w,
                              unsigned short* __restrict__ xb, int* __restrict__ meta) {
  const int wid = threadIdx.x >> 6;
  const int lane = threadIdx.x & 63;
  const int t = blockIdx.x * 4 + wid;
  __shared__ int cnt[NEXP];
  if (threadIdx.x < NEXP) cnt[threadIdx.x] = 0;
  const float4* xr = (const float4*)(x + (size_t)t * DDIM);
  float4 xv[4];
#pragma unroll
  for (int i = 0; i < 4; i++) xv[i] = xr[lane + 64 * i];
  // token-order bf16 copy of x (gemm1 gathers A rows from this)
  ushort4* xbr = (ushort4*)(xb + (size_t)t * DDIM);
#pragma unroll
  for (int i = 0; i < 4; i++) {
    ushort4 o;
    o.x = f2bf(xv[i].x); o.y = f2bf(xv[i].y); o.z = f2bf(xv[i].z); o.w = f2bf(xv[i].w);
    xbr[lane + 64 * i] = o;
  }
  float lg[NEXP];
#pragma unroll
  for (int e = 0; e < NEXP; e++) {
    const float4* we = (const float4*)(rw + e * DDIM);
    float s = 0.f;
#pragma unroll
    for (int i = 0; i < 4; i++) {
      float4 v = we[lane + 64 * i];
      s += xv[i].x * v.x + xv[i].y * v.y + xv[i].z * v.z + xv[i].w * v.w;
    }
#pragma unroll
    for (int m = 32; m > 0; m >>= 1) s += __shfl_xor(s, m, 64);
    lg[e] = s;
  }
  int i0 = 0; float m0 = lg[0];
#pragma unroll
  for (int e = 1; e < NEXP; e++) if (lg[e] > m0) { m0 = lg[e]; i0 = e; }
  int i1 = -1; float m1 = -3.0e38f;
#pragma unroll
  for (int e = 0; e < NEXP; e++) if (e != i0 && lg[e] > m1) { m1 = lg[e]; i1 = e; }
  __syncthreads();
  if (lane == 0) {
    float ee = __expf(m1 - m0);
    float w0 = 1.f / (1.f + ee);
    tk_idx[2 * t] = i0; tk_idx[2 * t + 1] = i1;
    tk_w[2 * t] = w0;  tk_w[2 * t + 1] = ee / (1.f + ee);
    atomicAdd(&cnt[i0], 1);
    atomicAdd(&cnt[i1], 1);
  }
  __syncthreads();
  if (threadIdx.x < NEXP)
    atomicAdd(&meta[META_CNT + threadIdx.x * 32], cnt[threadIdx.x]);
}

// ---------------- tiny scan: 128-padded segment offsets + mtile->expert map ----------------
__global__ void scan_kernel(int* __restrict__ meta) {
  int* counts_p = meta + META_CNT;
  int* offp     = meta + META_OFF;
  int* mexp     = meta + META_MEXP;
  __shared__ int soff[NEXP + 1];
  if (threadIdx.x == 0) {
    int acc = 0;
    for (int e = 0; e < NEXP; e++) {
      offp[e] = acc; soff[e] = acc;
      acc += (counts_p[e * 32] + 127) & ~127;
    }
    offp[NEXP] = acc; soff[NEXP] = acc;
  }
  __syncthreads();
  for (int m = threadIdx.x; m < NMT; m += blockDim.x) {
    int s = m * 128;
    int e = -1;
#pragma unroll
    for (int q = 0; q < NEXP; q++)
      if (s >= soff[q] && s < soff[q + 1]) { e = q; break; }
    mexp[m] = e;
  }
}

// ---------------- scatter: block-aggregated cursor reservation (8 atomics/block) ----------------
__global__ void scatter_kernel(const int* __restrict__ tk_idx, const float* __restrict__ tk_w,
                               int* __restrict__ meta,
                               int* __restrict__ slot_token, float* __restrict__ slot_w) {
  const int* offp = meta + META_OFF;
  int* cursors_p  = meta + META_CUR;
  int t = blockIdx.x * 256 + threadIdx.x;
  int w = threadIdx.x >> 6, lane = threadIdx.x & 63;
  int e0 = tk_idx[2 * t], e1 = tk_idx[2 * t + 1];
  unsigned long long lmask = (1ull << lane) - 1ull;
  __shared__ int cnt[4][NEXP], woff[4][NEXP], base[NEXP];
  int r0 = 0, r1 = 0;
#pragma unroll
  for (int e = 0; e < NEXP; e++) {
    unsigned long long m0 = __ballot(e0 == e), m1 = __ballot(e1 == e);
    int c0 = __popcll(m0);
    if (lane == 0) cnt[w][e] = c0 + __popcll(m1);
    if (e0 == e) r0 = __popcll(m0 & lmask);
    if (e1 == e) r1 = c0 + __popcll(m1 & lmask);
  }
  __syncthreads();
  if (threadIdx.x < NEXP) {
    int e = threadIdx.x, acc = 0;
#pragma unroll
    for (int ww = 0; ww < 4; ww++) { woff[ww][e] = acc; acc += cnt[ww][e]; }
    base[e] = atomicAdd(&cursors_p[e * 32], acc);
  }
  __syncthreads();
  int p0 = offp[e0] + base[e0] + woff[w][e0] + r0;
  int p1 = offp[e1] + base[e1] + woff[w][e1] + r1;
  slot_token[p0] = t; slot_w[p0] = tk_w[2 * t];
  slot_token[p1] = t; slot_w[p1] = tk_w[2 * t + 1];
}

// ---------------- fused fp32 -> bf16 conversion for all 3 weight tensors ----------------
#define W4EACH (1 << 22)  // (8*2048*1024)/4 float4s per tensor
__global__ void cvt3_kernel(const float* __restrict__ wg, const float* __restrict__ wu,
                            const float* __restrict__ wd,
                            unsigned short* __restrict__ wgb, unsigned short* __restrict__ wub,
                            unsigned short* __restrict__ wdb) {
  int i = blockIdx.x * blockDim.x + threadIdx.x;
  int stride = gridDim.x * blockDim.x;
  for (; i < 3 * W4EACH; i += stride) {
    int which = i >> 22, j = i & (W4EACH - 1);
    const float4* s = (const float4*)(which == 0 ? wg : which == 1 ? wu : wd);
    ushort4* d = (ushort4*)(which == 0 ? wgb : which == 1 ? wub : wdb);
    float4 v = s[j];
    ushort4 o;
    o.x = f2bf(v.x); o.y = f2bf(v.y); o.z = f2bf(v.z); o.w = f2bf(v.w);
    d[j] = o;
  }
}

// ---------------- GEMM1: h = silu(xb[tok]@wg^T) * (xb[tok]@wu^T), gathered A ----------------
// [R10-verified: 32x32x16 MFMA + deep swizzle s(row)=(row&7)^((row>>3)&7), 0 bank conflicts]
__global__ __launch_bounds__(256)
void gemm1_kernel(const unsigned short* __restrict__ xb,
                  const unsigned short* __restrict__ wgb,
                  const unsigned short* __restrict__ wub,
                  const int* __restrict__ meta,
                  const int* __restrict__ slot_token,
                  unsigned short* __restrict__ h, int m0) {
  const int gm = m0 + blockIdx.y;            // global mtile
  const int e = meta[META_MEXP + gm];
  if (e < 0) return;
  const int n0 = blockIdx.x * 64;            // F offset

  __shared__ alignas(16) unsigned short As[128 * 64];
  __shared__ alignas(16) unsigned short Bgs[64 * 64];
  __shared__ alignas(16) unsigned short Bus[64 * 64];

  const int tid = threadIdx.x;
  const int wid = tid >> 6;
  const int lane = tid & 63;
  const int wr = wid >> 1, wc = wid & 1;

  const char* const xbB = (const char*)xb;
  const char* const wgB = (const char*)wgb + ((size_t)e * FDIM + n0) * (DDIM * 2);
  const char* const wuB = (const char*)wub + ((size_t)e * FDIM + n0) * (DDIM * 2);

  const char* asrc[4]; unsigned int aldc[4];
#pragma unroll
  for (int q = 0; q < 4; q++) {
    int chunk = q * 4 + wid;
    int row = chunk * 8 + (lane >> 3);
    int tok = slot_token[gm * 128 + row];
    tok = tok < 0 ? 0 : tok;                 // pad rows: compute garbage, filtered in gemm2
    unsigned int sl = (unsigned int)((((lane & 7) ^ (lane >> 3) ^ chunk) & 7) << 4);
    asrc[q] = xbB + (size_t)tok * (DDIM * 2) + sl;
    aldc[q] = chunk * 1024;
  }
  const char* bgsrc[2]; const char* busrc[2]; unsigned int bldc[2];
#pragma unroll
  for (int q = 0; q < 2; q++) {
    int chunk = q * 4 + wid;
    int row = chunk * 8 + (lane >> 3);
    unsigned int sl = (unsigned int)((((lane & 7) ^ (lane >> 3) ^ chunk) & 7) << 4);
    bgsrc[q] = wgB + (size_t)row * (DDIM * 2) + sl;
    busrc[q] = wuB + (size_t)row * (DDIM * 2) + sl;
    bldc[q] = chunk * 1024;
  }

  // 32x32 fragment ds_read offsets, deep-swizzled
  const int l31 = lane & 31;
  const int lk2 = lane >> 5;                 // k-chunk selector (8 elems = 16B)
  const int lr3 = (lane >> 3) & 3;           // (l31>>3) — row-group within fragment
  unsigned int aoff[2][4], boff[4];
#pragma unroll
  for (int mf = 0; mf < 2; mf++) {
    unsigned int sa = (unsigned int)((((lane & 7) ^ (mf * 4 + lr3)) & 7) << 4);
#pragma unroll
    for (int kc = 0; kc < 4; kc++) {
      unsigned int lg = (unsigned int)(kc * 32 + lk2 * 16);
      aoff[mf][kc] = (unsigned int)(wr * 64 + mf * 32 + l31) * 128 + (lg ^ sa);
    }
  }
  {
    unsigned int sb = (unsigned int)((((lane & 7) ^ (wc * 4 + lr3)) & 7) << 4);
#pragma unroll
    for (int kc = 0; kc < 4; kc++) {
      unsigned int lg = (unsigned int)(kc * 32 + lk2 * 16);
      boff[kc] = (unsigned int)(wc * 32 + l31) * 128 + (lg ^ sb);
    }
  }

  f32x16 accg[2] = {};
  f32x16 accu[2] = {};
  const char* asb = (const char*)As;
  const char* bgsb = (const char*)Bgs;
  const char* busb = (const char*)Bus;

  for (int kt = 0; kt < DDIM / 64; kt++) {
    const int koff = kt * 128;
#pragma unroll
    for (int q = 0; q < 2; q++) {
      cp16((char*)Bgs + bldc[q], bgsrc[q] + koff);
      cp16((char*)Bus + bldc[q], busrc[q] + koff);
    }
#pragma unroll
    for (int q = 0; q < 4; q++) cp16((char*)As + aldc[q], asrc[q] + koff);
    __syncthreads();
#pragma unroll
    for (int kc = 0; kc < 4; kc++) {
      bf16x8 af0 = *(const bf16x8*)(asb + aoff[0][kc]);
      bf16x8 af1 = *(const bf16x8*)(asb + aoff[1][kc]);
      bf16x8 bg  = *(const bf16x8*)(bgsb + boff[kc]);
      bf16x8 bu  = *(const bf16x8*)(busb + boff[kc]);
      accg[0] = __builtin_amdgcn_mfma_f32_32x32x16_bf16(af0, bg, accg[0], 0, 0, 0);
      accg[1] = __builtin_amdgcn_mfma_f32_32x32x16_bf16(af1, bg, accg[1], 0, 0, 0);
      accu[0] = __builtin_amdgcn_mfma_f32_32x32x16_bf16(af0, bu, accu[0], 0, 0, 0);
      accu[1] = __builtin_amdgcn_mfma_f32_32x32x16_bf16(af1, bu, accu[1], 0, 0, 0);
    }
    __syncthreads();
  }

  // epilogue: h = silu(g)*u, bf16. 32x32 C/D map (m74/m101):
  // col = lane&31, row = (reg&3) + 8*(reg>>2) + 4*(lane>>5)
  unsigned short* hB = h + (size_t)(gm - m0) * 128 * FDIM;
  const int colw = n0 + wc * 32 + l31;
#pragma unroll
  for (int mf = 0; mf < 2; mf++) {
    f32x16 g = accg[mf], u = accu[mf];
#pragma unroll
    for (int reg = 0; reg < 16; reg++) {
      float gv = g[reg];
      float hv = (gv / (1.f + __expf(-gv))) * u[reg];
      int row = wr * 64 + mf * 32 + (reg & 3) + 8 * (reg >> 2) + 4 * lk2;
      hB[(size_t)row * FDIM + colw] = f2bf(hv);
    }
  }
}

// ---------------- GEMM2: out[token] += w * (h @ wd^T) ----------------
// R11: 32x32x16 MFMA + deep swizzle (mirror of verified gemm1 R9+R10 port).
// tile 128(slots) x 128(D), BK=64 over F. Wave tile 64x64 = 2x2 fragments of 32x32.
// 16 MFMA + 16 ds_read per K-step (was 32+16). 1D grid, XCD-chunked mtile-major (R4).
__global__ __launch_bounds__(256)
void gemm2_kernel(const unsigned short* __restrict__ h,
                  const unsigned short* __restrict__ wdb,
                  const int* __restrict__ meta,
                  const int* __restrict__ slot_token,
                  const float* __restrict__ slot_w,
                  float* __restrict__ out, int m0) {
  const int wgid = xcd_remap((int)blockIdx.x, (int)gridDim.x);
  const int gm = m0 + (wgid >> 3);
  const int e = meta[META_MEXP + gm];
  if (e < 0) return;
  const int n0 = (wgid & 7) * 128;           // D offset

  __shared__ alignas(16) unsigned short As[128 * 64];
  __shared__ alignas(16) unsigned short Bs[128 * 64];

  const int tid = threadIdx.x;
  const int wid = tid >> 6;
  const int lane = tid & 63;
  const int wr = wid >> 1, wc = wid & 1;

  const char* const hB = (const char*)h + (size_t)(gm - m0) * 128 * (FDIM * 2);
  const char* const wdB = (const char*)wdb + ((size_t)e * DDIM + n0) * (FDIM * 2);

  const char* asrc[4]; const char* bsrc[4]; unsigned int ldc[4];
#pragma unroll
  for (int q = 0; q < 4; q++) {
    int chunk = q * 4 + wid;
    int row = chunk * 8 + (lane >> 3);
    unsigned int sl = (unsigned int)((((lane & 7) ^ (lane >> 3) ^ chunk) & 7) << 4);
    asrc[q] = hB + (size_t)row * (FDIM * 2) + sl;
    bsrc[q] = wdB + (size_t)row * (FDIM * 2) + sl;
    ldc[q] = chunk * 1024;
  }

  // 32x32 fragment ds_read offsets, deep-swizzled
  const int l31 = lane & 31;
  const int lk2 = lane >> 5;
  const int lr3 = (lane >> 3) & 3;
  unsigned int aoff[2][4], boff[2][4];
#pragma unroll
  for (int mf = 0; mf < 2; mf++) {
    unsigned int sa = (unsigned int)((((lane & 7) ^ (mf * 4 + lr3)) & 7) << 4);
#pragma unroll
    for (int kc = 0; kc < 4; kc++) {
      unsigned int lg = (unsigned int)(kc * 32 + lk2 * 16);
      aoff[mf][kc] = (unsigned int)(wr * 64 + mf * 32 + l31) * 128 + (lg ^ sa);
    }
  }
#pragma unroll
  for (int nf = 0; nf < 2; nf++) {
    unsigned int sb = (unsigned int)((((lane & 7) ^ (nf * 4 + lr3)) & 7) << 4);
#pragma unroll
    for (int kc = 0; kc < 4; kc++) {
      unsigned int lg = (unsigned int)(kc * 32 + lk2 * 16);
      boff[nf][kc] = (unsigned int)(wc * 64 + nf * 32 + l31) * 128 + (lg ^ sb);
    }
  }

  f32x16 acc00 = {}, acc01 = {}, acc10 = {}, acc11 = {};
  const char* asb = (const char*)As;
  const char* bsb = (const char*)Bs;

  for (int kt = 0; kt < FDIM / 64; kt++) {
    const int koff = kt * 128;
#pragma unroll
    for (int q = 0; q < 4; q++) {
      cp16((char*)As + ldc[q], asrc[q] + koff);
      cp16((char*)Bs + ldc[q], bsrc[q] + koff);
    }
    __syncthreads();
#pragma unroll
    for (int kc = 0; kc < 4; kc++) {
      bf16x8 af0 = *(const bf16x8*)(asb + aoff[0][kc]);
      bf16x8 af1 = *(const bf16x8*)(asb + aoff[1][kc]);
      bf16x8 bf0 = *(const bf16x8*)(bsb + boff[0][kc]);
      bf16x8 bf1 = *(const bf16x8*)(bsb + boff[1][kc]);
      acc00 = __builtin_amdgcn_mfma_f32_32x32x16_bf16(af0, bf0, acc00, 0, 0, 0);
      acc01 = __builtin_amdgcn_mfma_f32_32x32x16_bf16(af0, bf1, acc01, 0, 0, 0);
      acc10 = __builtin_amdgcn_mfma_f32_32x32x16_bf16(af1, bf0, acc10, 0, 0, 0);
      acc11 = __builtin_amdgcn_mfma_f32_32x32x16_bf16(af1, bf1, acc11, 0, 0, 0);
    }
    __syncthreads();
  }

  // epilogue: exactly 2 commutative fp32 atomic adds per out element (deterministic).
  // 32x32 C/D map: col = lane&31, row = (reg&3) + 8*(reg>>2) + 4*(lane>>5)
#pragma unroll
  for (int mf = 0; mf < 2; mf++) {
    const f32x16 a0 = mf == 0 ? acc00 : acc10;
    const f32x16 a1 = mf == 0 ? acc01 : acc11;
#pragma unroll
    for (int reg = 0; reg < 16; reg++) {
      int row = wr * 64 + mf * 32 + (reg & 3) + 8 * (reg >> 2) + 4 * lk2;
      int slot = gm * 128 + row;
      int tok = slot_token[slot];
      if (tok < 0) continue;
      float w = slot_w[slot];
      float* orow = out + (size_t)tok * DDIM + n0 + wc * 64 + l31;
      atomicAdd(orow, w * a0[reg]);
      atomicAdd(orow + 32, w * a1[reg]);
    }
  }
}

// ---------------- workspace layout (no xg; xb replaces it; h windowed to fit) ----------------
static constexpr size_t WB       = (size_t)NEXP * FDIM * DDIM * 2;   // 33,554,432
static constexpr size_t OFF_WG   = 0;
static constexpr size_t OFF_WU   = OFF_WG + WB;
static constexpr size_t OFF_WD   = OFF_WU + WB;
static constexpr size_t OFF_XB   = OFF_WD + WB;                      // 100,663,296
static constexpr size_t XBB      = (size_t)T_TOK * DDIM * 2;         // 33,554,432
static constexpr size_t OFF_ST   = OFF_XB + XBB;                     // 134,217,728
static constexpr size_t OFF_SW   = OFF_ST + (size_t)MAX_SLOTS * 4;
static constexpr size_t OFF_TI   = OFF_SW + (size_t)MAX_SLOTS * 4;
static constexpr size_t OFF_TW   = OFF_TI + (size_t)T_TOK * 2 * 4;
static constexpr size_t OFF_META = OFF_TW + (size_t)T_TOK * 2 * 4;
static constexpr size_t OFF_H    = OFF_ST + 1048576;                 // 135,266,304
static constexpr size_t MT_BYTES = (size_t)128 * FDIM * 2;           // 512 KiB per mtile of h

extern "C" void kernel_launch(void* const* d_in, const int* in_sizes, int n_in,
                              void* d_out, int out_size, void* d_ws, size_t ws_size,
                              hipStream_t stream) {
  const float* x  = (const float*)d_in[0];
  const float* rw = (const float*)d_in[1];
  const float* wg = (const float*)d_in[2];
  const float* wu = (const float*)d_in[3];
  const float* wd = (const float*)d_in[4];
  float* out = (float*)d_out;

  char* ws = (char*)d_ws;
  unsigned short* wgb = (unsigned short*)(ws + OFF_WG);
  unsigned short* wub = (unsigned short*)(ws + OFF_WU);
  unsigned short* wdb = (unsigned short*)(ws + OFF_WD);
  unsigned short* xb  = (unsigned short*)(ws + OFF_XB);
  unsigned short* h   = (unsigned short*)(ws + OFF_H);
  int*   slot_token = (int*)(ws + OFF_ST);
  float* slot_w     = (float*)(ws + OFF_SW);
  int*   tk_idx     = (int*)(ws + OFF_TI);
  float* tk_w       = (float*)(ws + OFF_TW);
  int*   meta       = (int*)(ws + OFF_META);

  // h window size (mtiles) adapted to ws_size; deterministic per session
  size_t avail = ws_size > OFF_H ? ws_size - OFF_H : 0;
  int wmt = (int)(avail / MT_BYTES);
  if (wmt > NMT) wmt = NMT;
  if (wmt < 8) wmt = 8;

  (void)hipMemsetAsync(out, 0, (size_t)out_size * sizeof(float), stream);
  (void)hipMemsetAsync(meta, 0, 2048, stream);
  (void)hipMemsetAsync(slot_token, 0xFF, (size_t)MAX_SLOTS * 4, stream);

  cvt3_kernel<<<4096, 256, 0, stream>>>(wg, wu, wd, wgb, wub, wdb);
  router_kernel<<<T_TOK / 4, 256, 0, stream>>>(x, rw, tk_idx, tk_w, xb, meta);
  scan_kernel<<<1, 256, 0, stream>>>(meta);
  scatter_kernel<<<T_TOK / 256, 256, 0, stream>>>(tk_idx, tk_w, meta, slot_token, slot_w);

  for (int m0 = 0; m0 < NMT; m0 += wmt) {
    int mc = (NMT - m0 < wmt) ? (NMT - m0) : wmt;
    gemm1_kernel<<<dim3(FDIM / 64, mc), 256, 0, stream>>>(xb, wgb, wub, meta, slot_token, h, m0);
    gemm2_kernel<<<mc * 8, 256, 0, stream>>>(h, wdb, meta, slot_token, slot_w, out, m0);
  }
}

// Round 12
// 702.365 us; speedup vs baseline: 1.1270x; 1.1270x over previous
//
#include <hip/hip_runtime.h>
#include <stdint.h>

// Problem constants
#define T_TOK 16384   // B*S
#define DDIM  1024
#define FDIM  2048
#define NEXP  8
#define MAX_SLOTS 34816  // T*K (32768) + E*255 padding, rounded to 256
#define NMT (MAX_SLOTS / 128)  // 272 mtiles (128-slot units)

typedef __attribute__((ext_vector_type(8))) short bf16x8;
typedef __attribute__((ext_vector_type(4))) float f32x4;
typedef __attribute__((ext_vector_type(16))) float f32x16;

typedef __attribute__((address_space(1))) void gvoid_t;
typedef __attribute__((address_space(3))) void lvoid_t;

// meta layout (ints): [0..255] counts padded (stride 32), [256..511] cursors padded,
// [512..520] offp, [544..544+NMT) mexp
#define META_CNT 0
#define META_CUR 256
#define META_OFF 512
#define META_MEXP 544

__device__ __forceinline__ void cp16(void* lds, const void* g) {
  __builtin_amdgcn_global_load_lds((gvoid_t*)g, (lvoid_t*)lds, 16, 0, 0);
}

__device__ __forceinline__ unsigned short f2bf(float f) {
  union { float f; unsigned int u; } v; v.f = f;
  unsigned int u = v.u;
  return (unsigned short)((u + 0x7fffu + ((u >> 16) & 1u)) >> 16);  // RNE
}

// bijective XCD-chunk remap (m204) — gemm2 ONLY (h-tile locality; measured win R4).
// gemm1 keeps the natural 2D grid: bid%8 = nb%8 -> weight-column L2 affinity (measured R3).
__device__ __forceinline__ int xcd_remap(int bid, int nwg) {
  int xcd = bid & 7, i = bid >> 3;
  int q = nwg >> 3, r = nwg & 7;
  int base = (xcd < r) ? xcd * (q + 1) : r * (q + 1) + (xcd - r) * q;
  return base + i;
}

// ---------------- router: fp32 logits, top-2 weights; emits xb = bf16(x); fused histogram ----------------
__global__ void router_kernel(const float* __restrict__ x, const float* __restrict__ rw,
                              int* __restrict__ tk_idx, float* __restrict__ tk_w,
                              unsigned short* __restrict__ xb, int* __restrict__ meta) {
  const int wid = threadIdx.x >> 6;
  const int lane = threadIdx.x & 63;
  const int t = blockIdx.x * 4 + wid;
  __shared__ int cnt[NEXP];
  if (threadIdx.x < NEXP) cnt[threadIdx.x] = 0;
  const float4* xr = (const float4*)(x + (size_t)t * DDIM);
  float4 xv[4];
#pragma unroll
  for (int i = 0; i < 4; i++) xv[i] = xr[lane + 64 * i];
  // token-order bf16 copy of x (gemm1 gathers A rows from this)
  ushort4* xbr = (ushort4*)(xb + (size_t)t * DDIM);
#pragma unroll
  for (int i = 0; i < 4; i++) {
    ushort4 o;
    o.x = f2bf(xv[i].x); o.y = f2bf(xv[i].y); o.z = f2bf(xv[i].z); o.w = f2bf(xv[i].w);
    xbr[lane + 64 * i] = o;
  }
  float lg[NEXP];
#pragma unroll
  for (int e = 0; e < NEXP; e++) {
    const float4* we = (const float4*)(rw + e * DDIM);
    float s = 0.f;
#pragma unroll
    for (int i = 0; i < 4; i++) {
      float4 v = we[lane + 64 * i];
      s += xv[i].x * v.x + xv[i].y * v.y + xv[i].z * v.z + xv[i].w * v.w;
    }
#pragma unroll
    for (int m = 32; m > 0; m >>= 1) s += __shfl_xor(s, m, 64);
    lg[e] = s;
  }
  int i0 = 0; float m0 = lg[0];
#pragma unroll
  for (int e = 1; e < NEXP; e++) if (lg[e] > m0) { m0 = lg[e]; i0 = e; }
  int i1 = -1; float m1 = -3.0e38f;
#pragma unroll
  for (int e = 0; e < NEXP; e++) if (e != i0 && lg[e] > m1) { m1 = lg[e]; i1 = e; }
  __syncthreads();
  if (lane == 0) {
    float ee = __expf(m1 - m0);
    float w0 = 1.f / (1.f + ee);
    tk_idx[2 * t] = i0; tk_idx[2 * t + 1] = i1;
    tk_w[2 * t] = w0;  tk_w[2 * t + 1] = ee / (1.f + ee);
    atomicAdd(&cnt[i0], 1);
    atomicAdd(&cnt[i1], 1);
  }
  __syncthreads();
  if (threadIdx.x < NEXP)
    atomicAdd(&meta[META_CNT + threadIdx.x * 32], cnt[threadIdx.x]);
}

// ---------------- tiny scan: 256-padded segment offsets + mtile->expert map ----------------
// 256-padding guarantees every 2-mtile pair is single-expert (gemm2 BM=256).
__global__ void scan_kernel(int* __restrict__ meta) {
  int* counts_p = meta + META_CNT;
  int* offp     = meta + META_OFF;
  int* mexp     = meta + META_MEXP;
  __shared__ int soff[NEXP + 1];
  if (threadIdx.x == 0) {
    int acc = 0;
    for (int e = 0; e < NEXP; e++) {
      offp[e] = acc; soff[e] = acc;
      acc += (counts_p[e * 32] + 255) & ~255;
    }
    offp[NEXP] = acc; soff[NEXP] = acc;
  }
  __syncthreads();
  for (int m = threadIdx.x; m < NMT; m += blockDim.x) {
    int s = m * 128;
    int e = -1;
#pragma unroll
    for (int q = 0; q < NEXP; q++)
      if (s >= soff[q] && s < soff[q + 1]) { e = q; break; }
    mexp[m] = e;
  }
}

// ---------------- scatter: block-aggregated cursor reservation (8 atomics/block) ----------------
__global__ void scatter_kernel(const int* __restrict__ tk_idx, const float* __restrict__ tk_w,
                               int* __restrict__ meta,
                               int* __restrict__ slot_token, float* __restrict__ slot_w) {
  const int* offp = meta + META_OFF;
  int* cursors_p  = meta + META_CUR;
  int t = blockIdx.x * 256 + threadIdx.x;
  int w = threadIdx.x >> 6, lane = threadIdx.x & 63;
  int e0 = tk_idx[2 * t], e1 = tk_idx[2 * t + 1];
  unsigned long long lmask = (1ull << lane) - 1ull;
  __shared__ int cnt[4][NEXP], woff[4][NEXP], base[NEXP];
  int r0 = 0, r1 = 0;
#pragma unroll
  for (int e = 0; e < NEXP; e++) {
    unsigned long long m0 = __ballot(e0 == e), m1 = __ballot(e1 == e);
    int c0 = __popcll(m0);
    if (lane == 0) cnt[w][e] = c0 + __popcll(m1);
    if (e0 == e) r0 = __popcll(m0 & lmask);
    if (e1 == e) r1 = c0 + __popcll(m1 & lmask);
  }
  __syncthreads();
  if (threadIdx.x < NEXP) {
    int e = threadIdx.x, acc = 0;
#pragma unroll
    for (int ww = 0; ww < 4; ww++) { woff[ww][e] = acc; acc += cnt[ww][e]; }
    base[e] = atomicAdd(&cursors_p[e * 32], acc);
  }
  __syncthreads();
  int p0 = offp[e0] + base[e0] + woff[w][e0] + r0;
  int p1 = offp[e1] + base[e1] + woff[w][e1] + r1;
  slot_token[p0] = t; slot_w[p0] = tk_w[2 * t];
  slot_token[p1] = t; slot_w[p1] = tk_w[2 * t + 1];
}

// ---------------- fused fp32 -> bf16 conversion for all 3 weight tensors ----------------
#define W4EACH (1 << 22)  // (8*2048*1024)/4 float4s per tensor
__global__ void cvt3_kernel(const float* __restrict__ wg, const float* __restrict__ wu,
                            const float* __restrict__ wd,
                            unsigned short* __restrict__ wgb, unsigned short* __restrict__ wub,
                            unsigned short* __restrict__ wdb) {
  int i = blockIdx.x * blockDim.x + threadIdx.x;
  int stride = gridDim.x * blockDim.x;
  for (; i < 3 * W4EACH; i += stride) {
    int which = i >> 22, j = i & (W4EACH - 1);
    const float4* s = (const float4*)(which == 0 ? wg : which == 1 ? wu : wd);
    ushort4* d = (ushort4*)(which == 0 ? wgb : which == 1 ? wub : wdb);
    float4 v = s[j];
    ushort4 o;
    o.x = f2bf(v.x); o.y = f2bf(v.y); o.z = f2bf(v.z); o.w = f2bf(v.w);
    d[j] = o;
  }
}

// ---------------- GEMM1: h = silu(xb[tok]@wg^T) * (xb[tok]@wu^T), gathered A ----------------
// [R10-verified: 32x32x16 MFMA + deep swizzle s(row)=(row&7)^((row>>3)&7), 0 bank conflicts]
__global__ __launch_bounds__(256)
void gemm1_kernel(const unsigned short* __restrict__ xb,
                  const unsigned short* __restrict__ wgb,
                  const unsigned short* __restrict__ wub,
                  const int* __restrict__ meta,
                  const int* __restrict__ slot_token,
                  unsigned short* __restrict__ h, int m0) {
  const int gm = m0 + blockIdx.y;            // global mtile
  const int e = meta[META_MEXP + gm];
  if (e < 0) return;
  const int n0 = blockIdx.x * 64;            // F offset

  __shared__ alignas(16) unsigned short As[128 * 64];
  __shared__ alignas(16) unsigned short Bgs[64 * 64];
  __shared__ alignas(16) unsigned short Bus[64 * 64];

  const int tid = threadIdx.x;
  const int wid = tid >> 6;
  const int lane = tid & 63;
  const int wr = wid >> 1, wc = wid & 1;

  const char* const xbB = (const char*)xb;
  const char* const wgB = (const char*)wgb + ((size_t)e * FDIM + n0) * (DDIM * 2);
  const char* const wuB = (const char*)wub + ((size_t)e * FDIM + n0) * (DDIM * 2);

  const char* asrc[4]; unsigned int aldc[4];
#pragma unroll
  for (int q = 0; q < 4; q++) {
    int chunk = q * 4 + wid;
    int row = chunk * 8 + (lane >> 3);
    int tok = slot_token[gm * 128 + row];
    tok = tok < 0 ? 0 : tok;                 // pad rows: compute garbage, filtered in gemm2
    unsigned int sl = (unsigned int)((((lane & 7) ^ (lane >> 3) ^ chunk) & 7) << 4);
    asrc[q] = xbB + (size_t)tok * (DDIM * 2) + sl;
    aldc[q] = chunk * 1024;
  }
  const char* bgsrc[2]; const char* busrc[2]; unsigned int bldc[2];
#pragma unroll
  for (int q = 0; q < 2; q++) {
    int chunk = q * 4 + wid;
    int row = chunk * 8 + (lane >> 3);
    unsigned int sl = (unsigned int)((((lane & 7) ^ (lane >> 3) ^ chunk) & 7) << 4);
    bgsrc[q] = wgB + (size_t)row * (DDIM * 2) + sl;
    busrc[q] = wuB + (size_t)row * (DDIM * 2) + sl;
    bldc[q] = chunk * 1024;
  }

  // 32x32 fragment ds_read offsets, deep-swizzled
  const int l31 = lane & 31;
  const int lk2 = lane >> 5;                 // k-chunk selector (8 elems = 16B)
  const int lr3 = (lane >> 3) & 3;           // row-group within fragment
  unsigned int aoff[2][4], boff[4];
#pragma unroll
  for (int mf = 0; mf < 2; mf++) {
    unsigned int sa = (unsigned int)((((lane & 7) ^ (mf * 4 + lr3)) & 7) << 4);
#pragma unroll
    for (int kc = 0; kc < 4; kc++) {
      unsigned int lg = (unsigned int)(kc * 32 + lk2 * 16);
      aoff[mf][kc] = (unsigned int)(wr * 64 + mf * 32 + l31) * 128 + (lg ^ sa);
    }
  }
  {
    unsigned int sb = (unsigned int)((((lane & 7) ^ (wc * 4 + lr3)) & 7) << 4);
#pragma unroll
    for (int kc = 0; kc < 4; kc++) {
      unsigned int lg = (unsigned int)(kc * 32 + lk2 * 16);
      boff[kc] = (unsigned int)(wc * 32 + l31) * 128 + (lg ^ sb);
    }
  }

  f32x16 accg[2] = {};
  f32x16 accu[2] = {};
  const char* asb = (const char*)As;
  const char* bgsb = (const char*)Bgs;
  const char* busb = (const char*)Bus;

  for (int kt = 0; kt < DDIM / 64; kt++) {
    const int koff = kt * 128;
#pragma unroll
    for (int q = 0; q < 2; q++) {
      cp16((char*)Bgs + bldc[q], bgsrc[q] + koff);
      cp16((char*)Bus + bldc[q], busrc[q] + koff);
    }
#pragma unroll
    for (int q = 0; q < 4; q++) cp16((char*)As + aldc[q], asrc[q] + koff);
    __syncthreads();
#pragma unroll
    for (int kc = 0; kc < 4; kc++) {
      bf16x8 af0 = *(const bf16x8*)(asb + aoff[0][kc]);
      bf16x8 af1 = *(const bf16x8*)(asb + aoff[1][kc]);
      bf16x8 bg  = *(const bf16x8*)(bgsb + boff[kc]);
      bf16x8 bu  = *(const bf16x8*)(busb + boff[kc]);
      accg[0] = __builtin_amdgcn_mfma_f32_32x32x16_bf16(af0, bg, accg[0], 0, 0, 0);
      accg[1] = __builtin_amdgcn_mfma_f32_32x32x16_bf16(af1, bg, accg[1], 0, 0, 0);
      accu[0] = __builtin_amdgcn_mfma_f32_32x32x16_bf16(af0, bu, accu[0], 0, 0, 0);
      accu[1] = __builtin_amdgcn_mfma_f32_32x32x16_bf16(af1, bu, accu[1], 0, 0, 0);
    }
    __syncthreads();
  }

  // epilogue: h = silu(g)*u, bf16. 32x32 C/D map (m74/m101):
  // col = lane&31, row = (reg&3) + 8*(reg>>2) + 4*(lane>>5)
  unsigned short* hB = h + (size_t)(gm - m0) * 128 * FDIM;
  const int colw = n0 + wc * 32 + l31;
#pragma unroll
  for (int mf = 0; mf < 2; mf++) {
    f32x16 g = accg[mf], u = accu[mf];
#pragma unroll
    for (int reg = 0; reg < 16; reg++) {
      float gv = g[reg];
      float hv = (gv / (1.f + __expf(-gv))) * u[reg];
      int row = wr * 64 + mf * 32 + (reg & 3) + 8 * (reg >> 2) + 4 * lk2;
      hB[(size_t)row * FDIM + colw] = f2bf(hv);
    }
  }
}

// ---------------- GEMM2: out[token] += w * (h @ wd^T) ----------------
// R12: 16x16 fragment math reverted (R8-verified); BM=256 via 512 threads (8 waves 4x2).
// tile 256(slots) x 128(D), BK=64 over F. Per-wave tile 64x64 unchanged (VGPR ~88).
// wd[e] logical traffic halves (read once per 256 slots). LDS 48KB -> 2 blocks/CU (16 waves).
// 1D grid, XCD-chunked (R4): all 8 n-blocks of an mtile-pair on one XCD -> h L2-resident.
__global__ __launch_bounds__(512)
void gemm2_kernel(const unsigned short* __restrict__ h,
                  const unsigned short* __restrict__ wdb,
                  const int* __restrict__ meta,
                  const int* __restrict__ slot_token,
                  const float* __restrict__ slot_w,
                  float* __restrict__ out, int m0) {
  const int wgid = xcd_remap((int)blockIdx.x, (int)gridDim.x);
  const int gm = m0 + (wgid >> 3) * 2;       // first 128-mtile of the pair (256-pad: single expert)
  const int e = meta[META_MEXP + gm];
  if (e < 0) return;
  const int n0 = (wgid & 7) * 128;           // D offset

  __shared__ alignas(16) unsigned short As[256 * 64];  // 32 KB
  __shared__ alignas(16) unsigned short Bs[128 * 64];  // 16 KB

  const int tid = threadIdx.x;
  const int wid = tid >> 6;                  // 0..7
  const int lane = tid & 63;
  const int wr = wid >> 1, wc = wid & 1;     // 4 x 2 wave grid

  const unsigned int slog = (unsigned int)(((lane & 7) ^ (lane >> 3)) << 4);
  const char* const hB = (const char*)h + (size_t)(gm - m0) * 128 * (FDIM * 2);
  const char* const wdB = (const char*)wdb + ((size_t)e * DDIM + n0) * (FDIM * 2);

  const char* asrc[4]; unsigned int aldc[4];
#pragma unroll
  for (int q = 0; q < 4; q++) {
    int chunk = q * 8 + wid;                 // 32 chunks of 1KB = 32KB As
    int row = chunk * 8 + (lane >> 3);       // 0..255
    asrc[q] = hB + (size_t)row * (FDIM * 2) + slog;
    aldc[q] = chunk * 1024;
  }
  const char* bsrc[2]; unsigned int bldc[2];
#pragma unroll
  for (int q = 0; q < 2; q++) {
    int chunk = q * 8 + wid;                 // 16 chunks = 16KB Bs
    int row = chunk * 8 + (lane >> 3);       // 0..127
    bsrc[q] = wdB + (size_t)row * (FDIM * 2) + slog;
    bldc[q] = chunk * 1024;
  }

  const int lr = lane & 15, lk = lane >> 4;
  const unsigned int fsw = (unsigned int)((lane & 7) << 4);
  unsigned int aoff[4][2], boff[4][2];
#pragma unroll
  for (int f = 0; f < 4; f++)
#pragma unroll
    for (int kc = 0; kc < 2; kc++) {
      unsigned int lg = (unsigned int)(kc * 64 + lk * 16);
      aoff[f][kc] = (unsigned int)(wr * 64 + f * 16 + lr) * 128 + (lg ^ fsw);
      boff[f][kc] = (unsigned int)(wc * 64 + f * 16 + lr) * 128 + (lg ^ fsw);
    }

  f32x4 acc[4][4] = {};
  const char* asb = (const char*)As;
  const char* bsb = (const char*)Bs;

  for (int kt = 0; kt < FDIM / 64; kt++) {
    const int koff = kt * 128;
#pragma unroll
    for (int q = 0; q < 4; q++) cp16((char*)As + aldc[q], asrc[q] + koff);
#pragma unroll
    for (int q = 0; q < 2; q++) cp16((char*)Bs + bldc[q], bsrc[q] + koff);
    __syncthreads();
#pragma unroll
    for (int kc = 0; kc < 2; kc++) {
      bf16x8 af[4], bff[4];
#pragma unroll
      for (int mf = 0; mf < 4; mf++) af[mf] = *(const bf16x8*)(asb + aoff[mf][kc]);
#pragma unroll
      for (int nf = 0; nf < 4; nf++) bff[nf] = *(const bf16x8*)(bsb + boff[nf][kc]);
#pragma unroll
      for (int mf = 0; mf < 4; mf++)
#pragma unroll
        for (int nf = 0; nf < 4; nf++)
          acc[mf][nf] = __builtin_amdgcn_mfma_f32_16x16x32_bf16(af[mf], bff[nf], acc[mf][nf], 0, 0, 0);
    }
    __syncthreads();
  }

  // epilogue: exactly 2 commutative fp32 atomic adds per out element (deterministic)
#pragma unroll
  for (int mf = 0; mf < 4; mf++)
#pragma unroll
    for (int j = 0; j < 4; j++) {
      int slot = gm * 128 + wr * 64 + mf * 16 + lk * 4 + j;
      int tok = slot_token[slot];
      if (tok < 0) continue;
      float w = slot_w[slot];
      float* orow = out + (size_t)tok * DDIM + n0 + wc * 64 + lr;
#pragma unroll
      for (int nf = 0; nf < 4; nf++)
        atomicAdd(orow + nf * 16, w * acc[mf][nf][j]);
    }
}

// ---------------- workspace layout (no xg; xb replaces it; h windowed to fit) ----------------
static constexpr size_t WB       = (size_t)NEXP * FDIM * DDIM * 2;   // 33,554,432
static constexpr size_t OFF_WG   = 0;
static constexpr size_t OFF_WU   = OFF_WG + WB;
static constexpr size_t OFF_WD   = OFF_WU + WB;
static constexpr size_t OFF_XB   = OFF_WD + WB;                      // 100,663,296
static constexpr size_t XBB      = (size_t)T_TOK * DDIM * 2;         // 33,554,432
static constexpr size_t OFF_ST   = OFF_XB + XBB;                     // 134,217,728
static constexpr size_t OFF_SW   = OFF_ST + (size_t)MAX_SLOTS * 4;
static constexpr size_t OFF_TI   = OFF_SW + (size_t)MAX_SLOTS * 4;
static constexpr size_t OFF_TW   = OFF_TI + (size_t)T_TOK * 2 * 4;
static constexpr size_t OFF_META = OFF_TW + (size_t)T_TOK * 2 * 4;
static constexpr size_t OFF_H    = OFF_ST + 1048576;                 // 135,266,304
static constexpr size_t MT_BYTES = (size_t)128 * FDIM * 2;           // 512 KiB per mtile of h

extern "C" void kernel_launch(void* const* d_in, const int* in_sizes, int n_in,
                              void* d_out, int out_size, void* d_ws, size_t ws_size,
                              hipStream_t stream) {
  const float* x  = (const float*)d_in[0];
  const float* rw = (const float*)d_in[1];
  const float* wg = (const float*)d_in[2];
  const float* wu = (const float*)d_in[3];
  const float* wd = (const float*)d_in[4];
  float* out = (float*)d_out;

  char* ws = (char*)d_ws;
  unsigned short* wgb = (unsigned short*)(ws + OFF_WG);
  unsigned short* wub = (unsigned short*)(ws + OFF_WU);
  unsigned short* wdb = (unsigned short*)(ws + OFF_WD);
  unsigned short* xb  = (unsigned short*)(ws + OFF_XB);
  unsigned short* h   = (unsigned short*)(ws + OFF_H);
  int*   slot_token = (int*)(ws + OFF_ST);
  float* slot_w     = (float*)(ws + OFF_SW);
  int*   tk_idx     = (int*)(ws + OFF_TI);
  float* tk_w       = (float*)(ws + OFF_TW);
  int*   meta       = (int*)(ws + OFF_META);

  // h window size (mtiles) adapted to ws_size; even so gemm2's 256-slot pairs align
  size_t avail = ws_size > OFF_H ? ws_size - OFF_H : 0;
  int wmt = (int)(avail / MT_BYTES);
  if (wmt > NMT) wmt = NMT;
  wmt &= ~1;
  if (wmt < 8) wmt = 8;

  (void)hipMemsetAsync(out, 0, (size_t)out_size * sizeof(float), stream);
  (void)hipMemsetAsync(meta, 0, 2048, stream);
  (void)hipMemsetAsync(slot_token, 0xFF, (size_t)MAX_SLOTS * 4, stream);

  cvt3_kernel<<<4096, 256, 0, stream>>>(wg, wu, wd, wgb, wub, wdb);
  router_kernel<<<T_TOK / 4, 256, 0, stream>>>(x, rw, tk_idx, tk_w, xb, meta);
  scan_kernel<<<1, 256, 0, stream>>>(meta);
  scatter_kernel<<<T_TOK / 256, 256, 0, stream>>>(tk_idx, tk_w, meta, slot_token, slot_w);

  for (int m0 = 0; m0 < NMT; m0 += wmt) {
    int mc = (NMT - m0 < wmt) ? (NMT - m0) : wmt;
    gemm1_kernel<<<dim3(FDIM / 64, mc), 256, 0, stream>>>(xb, wgb, wub, meta, slot_token, h, m0);
    gemm2_kernel<<<(mc / 2) * 8, 512, 0, stream>>>(h, wdb, meta, slot_token, slot_w, out, m0);
  }
}